// Round 1
// baseline (322.181 us; speedup 1.0000x reference)
//
#include <hip/hip_runtime.h>

// ZBL screened repulsion + sorted segment sum.
// Inputs (per reference setup_inputs order):
//   d_in[0] Z      int32  [500000]
//   d_in[1] Dij    fp32   [16000000]
//   d_in[2] idx_i  int32  [16000000]  (sorted)
//   d_in[3] idx_j  int32  [16000000]
//   d_in[4] p      fp32   [1]
//   d_in[5] d      fp32   [1]
//   d_in[6] c      fp32   [4]
//   d_in[7] a      fp32   [4]
// Output: fp32 [500000] segment_sum over idx_i.

#define EPT 16          // edges per thread (E = 16e6 is divisible by 16)
#define BLOCK 256

__device__ __forceinline__ float fast_exp2(float x) {
#if defined(__has_builtin)
#if __has_builtin(__builtin_amdgcn_exp2f)
    return __builtin_amdgcn_exp2f(x);   // v_exp_f32 directly
#else
    return exp2f(x);
#endif
#else
    return exp2f(x);
#endif
}

// Per-atom Z^p table (kills 32M per-edge powf; table is 2MB -> lives in L2).
__global__ void __launch_bounds__(BLOCK) zbl_pow_kernel(
    const int* __restrict__ Z, const float* __restrict__ p,
    float* __restrict__ zp, int n)
{
    int i = blockIdx.x * BLOCK + threadIdx.x;
    if (i < n) {
        zp[i] = powf((float)Z[i], p[0]);   // Z in [0,94); 0^p = 0 ok
    }
}

__global__ void __launch_bounds__(BLOCK) zbl_edge_kernel(
    const float* __restrict__ Dij,
    const int*   __restrict__ idx_i,
    const int*   __restrict__ idx_j,
    const float* __restrict__ zp,
    const float* __restrict__ dptr,
    const float* __restrict__ c,
    const float* __restrict__ a,
    float* __restrict__ out,
    long long E)
{
    const long long t    = (long long)blockIdx.x * BLOCK + threadIdx.x;
    const long long base = t * EPT;
    if (base >= E) return;

    // Uniform scalars: fold 1/d and log2(e) into the exponent multipliers.
    const float LOG2E = 1.4426950408889634f;
    const float invd  = 1.0f / dptr[0];
    const float m0 = -a[0] * LOG2E * invd;
    const float m1 = -a[1] * LOG2E * invd;
    const float m2 = -a[2] * LOG2E * invd;
    const float m3 = -a[3] * LOG2E * invd;
    const float c0 = c[0], c1 = c[1], c2 = c[2], c3 = c[3];

    int   cur = idx_i[base];
    float acc = 0.0f;

#define PROC(I, J, D)                                                    \
    {                                                                    \
        const int   _i = (I);                                            \
        const float _t = (D) * (zp[_i] + zp[(J)]);                       \
        float _v;                                                        \
        _v = c0 * fast_exp2(m0 * _t);                                    \
        _v = fmaf(c1, fast_exp2(m1 * _t), _v);                           \
        _v = fmaf(c2, fast_exp2(m2 * _t), _v);                           \
        _v = fmaf(c3, fast_exp2(m3 * _t), _v);                           \
        if (_i != cur) { atomicAdd(out + cur, acc); acc = 0.0f; cur = _i; } \
        acc += _v;                                                       \
    }

    if (base + EPT <= E) {
        // Fast path: 16B vector loads (base is 64B-aligned since EPT=16).
#pragma unroll
        for (int v = 0; v < EPT; v += 4) {
            const float4 dj = *reinterpret_cast<const float4*>(Dij  + base + v);
            const int4   ii = *reinterpret_cast<const int4*>(idx_i + base + v);
            const int4   jj = *reinterpret_cast<const int4*>(idx_j + base + v);
            PROC(ii.x, jj.x, dj.x);
            PROC(ii.y, jj.y, dj.y);
            PROC(ii.z, jj.z, dj.z);
            PROC(ii.w, jj.w, dj.w);
        }
    } else {
        for (long long e = base; e < E; ++e) {
            PROC(idx_i[e], idx_j[e], Dij[e]);
        }
    }
#undef PROC

    atomicAdd(out + cur, acc);
}

extern "C" void kernel_launch(void* const* d_in, const int* in_sizes, int n_in,
                              void* d_out, int out_size, void* d_ws, size_t ws_size,
                              hipStream_t stream)
{
    const int*   Z     = (const int*)  d_in[0];
    const float* Dij   = (const float*)d_in[1];
    const int*   idx_i = (const int*)  d_in[2];
    const int*   idx_j = (const int*)  d_in[3];
    const float* p     = (const float*)d_in[4];
    const float* d     = (const float*)d_in[5];
    const float* c     = (const float*)d_in[6];
    const float* a     = (const float*)d_in[7];
    float*       out   = (float*)d_out;

    const int       nAtoms = in_sizes[0];
    const long long E      = in_sizes[1];
    float*          zp     = (float*)d_ws;   // nAtoms floats (2 MB) scratch

    // d_out is poisoned 0xAA before every timed launch; segment_sum needs zeros.
    hipMemsetAsync(d_out, 0, (size_t)out_size * sizeof(float), stream);

    zbl_pow_kernel<<<(nAtoms + BLOCK - 1) / BLOCK, BLOCK, 0, stream>>>(Z, p, zp, nAtoms);

    const long long nThreads = (E + EPT - 1) / EPT;
    const int       nBlocks  = (int)((nThreads + BLOCK - 1) / BLOCK);
    zbl_edge_kernel<<<nBlocks, BLOCK, 0, stream>>>(Dij, idx_i, idx_j, zp, d, c, a, out, E);
}

// Round 2
// 273.051 us; speedup vs baseline: 1.1799x; 1.1799x over previous
//
#include <hip/hip_runtime.h>

// ZBL screened repulsion + sorted segment sum.
//   d_in[0] Z int32[500000], d_in[1] Dij fp32[16e6], d_in[2] idx_i int32[16e6] (sorted),
//   d_in[3] idx_j int32[16e6], d_in[4] p, d_in[5] d, d_in[6] c[4], d_in[7] a[4]
// Output: fp32[500000] segment_sum over idx_i.
//
// Round 2: Z fits in uint8 (Z<94). Random per-edge gathers hit a 0.5MB byte
// table (L2-resident under streaming) instead of a 2MB float table (was being
// evicted -> 240MB HBM over-fetch). pow(z,p) becomes a 94-entry LDS lookup.
// All loads for a thread's 16 edges are issued before compute to raise MLP.

#define EPT   16        // edges per thread
#define BLOCK 256
#define MAXZ  95

__device__ __forceinline__ float fast_exp2(float x) {
#if __has_builtin(__builtin_amdgcn_exp2f)
    return __builtin_amdgcn_exp2f(x);   // v_exp_f32
#else
    return exp2f(x);
#endif
}

// Stage: compress Z to bytes; compute the 94-entry pow table once.
__global__ void __launch_bounds__(BLOCK) zbl_stage_kernel(
    const int* __restrict__ Z, const float* __restrict__ p,
    unsigned char* __restrict__ z8, float* __restrict__ ptab, int n)
{
    int i = blockIdx.x * BLOCK + threadIdx.x;
    if (i < MAXZ) ptab[i] = powf((float)i, p[0]);   // 0^p = 0, correct
    if (i < n)    z8[i] = (unsigned char)Z[i];
}

__global__ void __launch_bounds__(BLOCK) zbl_edge_kernel(
    const float*         __restrict__ Dij,
    const int*           __restrict__ idx_i,
    const int*           __restrict__ idx_j,
    const unsigned char* __restrict__ z8,
    const float*         __restrict__ ptab_g,
    const float*         __restrict__ dptr,
    const float*         __restrict__ c,
    const float*         __restrict__ a,
    float*               __restrict__ out,
    long long E)
{
    __shared__ float pt[MAXZ + 1];
    for (int k = threadIdx.x; k < MAXZ; k += BLOCK) pt[k] = ptab_g[k];
    __syncthreads();

    const long long t    = (long long)blockIdx.x * BLOCK + threadIdx.x;
    const long long base = t * EPT;
    if (base >= E) return;

    const float LOG2E = 1.4426950408889634f;
    const float invd  = 1.0f / dptr[0];
    const float m0 = -a[0] * LOG2E * invd;
    const float m1 = -a[1] * LOG2E * invd;
    const float m2 = -a[2] * LOG2E * invd;
    const float m3 = -a[3] * LOG2E * invd;
    const float c0 = c[0], c1 = c[1], c2 = c[2], c3 = c[3];

    if (base + EPT <= E) {
        // Phase 1: stream all 16 edges into registers (12 x dwordx4 loads).
        float dv[EPT];
        int   iv[EPT], jv[EPT];
#pragma unroll
        for (int v = 0; v < EPT; v += 4) {
            const float4 dq = *reinterpret_cast<const float4*>(Dij  + base + v);
            const int4   iq = *reinterpret_cast<const int4*>(idx_i + base + v);
            const int4   jq = *reinterpret_cast<const int4*>(idx_j + base + v);
            dv[v] = dq.x; dv[v+1] = dq.y; dv[v+2] = dq.z; dv[v+3] = dq.w;
            iv[v] = iq.x; iv[v+1] = iq.y; iv[v+2] = iq.z; iv[v+3] = iq.w;
            jv[v] = jq.x; jv[v+1] = jq.y; jv[v+2] = jq.z; jv[v+3] = jq.w;
        }
        // Phase 2: issue all 32 byte-gathers (0.5MB table -> L2 hits).
        int zi[EPT], zj[EPT];
#pragma unroll
        for (int k = 0; k < EPT; ++k) {
            zi[k] = z8[iv[k]];
            zj[k] = z8[jv[k]];
        }
        // Phase 3: compute + segmented accumulate (idx_i sorted).
        int   cur = iv[0];
        float acc = 0.0f;
#pragma unroll
        for (int k = 0; k < EPT; ++k) {
            const float tt = dv[k] * (pt[zi[k]] + pt[zj[k]]);
            float v;
            v = c0 * fast_exp2(m0 * tt);
            v = fmaf(c1, fast_exp2(m1 * tt), v);
            v = fmaf(c2, fast_exp2(m2 * tt), v);
            v = fmaf(c3, fast_exp2(m3 * tt), v);
            if (iv[k] != cur) { atomicAdd(out + cur, acc); acc = 0.0f; cur = iv[k]; }
            acc += v;
        }
        atomicAdd(out + cur, acc);
    } else {
        int   cur = idx_i[base];
        float acc = 0.0f;
        for (long long e = base; e < E; ++e) {
            const int   i  = idx_i[e];
            const float tt = Dij[e] * (pt[z8[i]] + pt[z8[idx_j[e]]]);
            float v;
            v = c0 * fast_exp2(m0 * tt);
            v = fmaf(c1, fast_exp2(m1 * tt), v);
            v = fmaf(c2, fast_exp2(m2 * tt), v);
            v = fmaf(c3, fast_exp2(m3 * tt), v);
            if (i != cur) { atomicAdd(out + cur, acc); acc = 0.0f; cur = i; }
            acc += v;
        }
        atomicAdd(out + cur, acc);
    }
}

extern "C" void kernel_launch(void* const* d_in, const int* in_sizes, int n_in,
                              void* d_out, int out_size, void* d_ws, size_t ws_size,
                              hipStream_t stream)
{
    const int*   Z     = (const int*)  d_in[0];
    const float* Dij   = (const float*)d_in[1];
    const int*   idx_i = (const int*)  d_in[2];
    const int*   idx_j = (const int*)  d_in[3];
    const float* p     = (const float*)d_in[4];
    const float* d     = (const float*)d_in[5];
    const float* c     = (const float*)d_in[6];
    const float* a     = (const float*)d_in[7];
    float*       out   = (float*)d_out;

    const int       nAtoms = in_sizes[0];
    const long long E      = in_sizes[1];

    // ws layout: [z8: nAtoms bytes][pad to 64][ptab: MAXZ floats]
    unsigned char* z8   = (unsigned char*)d_ws;
    const size_t   poff = ((size_t)nAtoms + 63) & ~(size_t)63;
    float*         ptab = (float*)((char*)d_ws + poff);

    // d_out is re-poisoned 0xAA before every timed launch; we need zeros.
    hipMemsetAsync(d_out, 0, (size_t)out_size * sizeof(float), stream);

    zbl_stage_kernel<<<(nAtoms + BLOCK - 1) / BLOCK, BLOCK, 0, stream>>>(Z, p, z8, ptab, nAtoms);

    const long long nThreads = (E + EPT - 1) / EPT;
    const int       nBlocks  = (int)((nThreads + BLOCK - 1) / BLOCK);
    zbl_edge_kernel<<<nBlocks, BLOCK, 0, stream>>>(Dij, idx_i, idx_j, z8, ptab, d, c, a, out, E);
}